// Round 6
// baseline (705.779 us; speedup 1.0000x reference)
//
#include <hip/hip_runtime.h>
#include <hip/hip_bf16.h>

#define N_TASK 100000
#define N_DATA 50000
#define NE     1500000
// D_TASK = D_DATA = 64, D_EDGE = 16, H = 2, C = 64, H*C = 128
#define SCAN_B 1024
#define NB_SCAN 98   // ceil(100000/1024)

typedef _Float16 half2v __attribute__((ext_vector_type(2)));

__device__ __forceinline__ unsigned pack_f16(float a, float b) {
    half2v h = {(_Float16)a, (_Float16)b};
    return __builtin_bit_cast(unsigned, h);
}
__device__ __forceinline__ float f16_lo(unsigned u) {
    half2v h = __builtin_bit_cast(half2v, u); return (float)h.x;
}
__device__ __forceinline__ float f16_hi(unsigned u) {
    half2v h = __builtin_bit_cast(half2v, u); return (float)h.y;
}
// f32 += f16x2 . f16x2 (v_dot2_f32_f16), with scalar fallback
__device__ __forceinline__ float fdot2f(unsigned a, unsigned b, float c) {
#if __has_builtin(__builtin_amdgcn_fdot2)
    return __builtin_amdgcn_fdot2(__builtin_bit_cast(half2v, a),
                                  __builtin_bit_cast(half2v, b), c, false);
#else
    return c + f16_lo(a) * f16_lo(b) + f16_hi(a) * f16_hi(b);
#endif
}

// ---- gemms: x_l and x_r rows -> packed f16 pairs; +1 block packs W_e -------
// blocks [0,12500): x_l rows; [12500,37500): x_r rows; block 37500: Wp
__global__ __launch_bounds__(256) void gemm_pre(
    const float* __restrict__ data_x, const float* __restrict__ Wl,
    const float* __restrict__ bl,
    const float* __restrict__ task_x, const float* __restrict__ Wr,
    const float* __restrict__ br,
    const float* __restrict__ We,
    unsigned* __restrict__ xlb, unsigned* __restrict__ xrb,
    unsigned* __restrict__ Wp)
{
    int b = blockIdx.x;
    int lane = threadIdx.x & 63;
    if (b < 12500) {
        int row = b * 4 + (threadIdx.x >> 6);
        float xv = data_x[(size_t)row * 64 + lane];
        float2 acc = *(const float2*)(bl + lane * 2);
#pragma unroll 16
        for (int k = 0; k < 64; ++k) {
            float xk = __shfl(xv, k);
            float2 w2 = *(const float2*)(Wl + k * 128 + lane * 2);
            acc.x += xk * w2.x; acc.y += xk * w2.y;
        }
        xlb[(size_t)row * 64 + lane] = pack_f16(acc.x, acc.y);
    } else if (b < 37500) {
        int row = (b - 12500) * 4 + (threadIdx.x >> 6);
        float xv = task_x[(size_t)row * 64 + lane];
        float2 acc = *(const float2*)(br + lane * 2);
#pragma unroll 16
        for (int k = 0; k < 64; ++k) {
            float xk = __shfl(xv, k);
            float2 w2 = *(const float2*)(Wr + k * 128 + lane * 2);
            acc.x += xk * w2.x; acc.y += xk * w2.y;
        }
        xrb[(size_t)row * 64 + lane] = pack_f16(acc.x, acc.y);
    } else {
#pragma unroll
        for (int r = 0; r < 4; ++r) {
            int idx = threadIdx.x * 4 + r;          // kp*128 + col
            int kp = idx >> 7, col = idx & 127;
            Wp[idx] = pack_f16(We[(2 * kp) * 128 + col],
                               We[(2 * kp + 1) * 128 + col]);
        }
    }
}

// ---- edge_attr -> f16 pairs, fully coalesced linear copy -------------------
// thread g: reads float4 at ea+4g (wave: 1KB contiguous), writes uint2 at 2g
__global__ __launch_bounds__(256) void ea_pack(
    const float4* __restrict__ ea4, uint2* __restrict__ eafu2)
{
    int g = blockIdx.x * blockDim.x + threadIdx.x;
    if (g >= NE * 4) return;                 // NE*16 floats / 4
    float4 q = ea4[g];
    uint2 o;
    o.x = pack_f16(q.x, q.y);
    o.y = pack_f16(q.z, q.w);
    eafu2[g] = o;
}

// ---- dst histogram: 4 edges/thread, coalesced int4 reads -------------------
__global__ __launch_bounds__(256) void hist_k(
    const int4* __restrict__ dst4, int* __restrict__ hist)
{
    int g = blockIdx.x * blockDim.x + threadIdx.x;
    if (g >= NE / 4) return;
    int4 d = dst4[g];
    atomicAdd(&hist[d.x], 1);
    atomicAdd(&hist[d.y], 1);
    atomicAdd(&hist[d.z], 1);
    atomicAdd(&hist[d.w], 1);
}

// ---- single-kernel decoupled-lookback exclusive scan -----------------------
__global__ __launch_bounds__(SCAN_B) void scan_lookback(
    const int* __restrict__ hist, unsigned long long* __restrict__ flags,
    int* __restrict__ start, int* __restrict__ cursor)
{
    __shared__ int s[SCAN_B];
    __shared__ int ex_sh;
    int tid = threadIdx.x, b = blockIdx.x;
    int i = b * SCAN_B + tid;
    int v = (i < N_TASK) ? hist[i] : 0;
    s[tid] = v;
    __syncthreads();
#pragma unroll
    for (int off = 1; off < SCAN_B; off <<= 1) {
        int t = (tid >= off) ? s[tid - off] : 0;
        __syncthreads();
        s[tid] += t;
        __syncthreads();
    }
    int incl = s[tid];
    if (tid == 0) {
        int total = s[SCAN_B - 1];
        __hip_atomic_store(&flags[b], (1ULL << 32) | (unsigned)total,
                           __ATOMIC_RELEASE, __HIP_MEMORY_SCOPE_AGENT);
        int ex = 0;
        for (int p = b - 1; p >= 0; --p) {
            unsigned long long f;
            do {
                f = __hip_atomic_load(&flags[p], __ATOMIC_ACQUIRE,
                                      __HIP_MEMORY_SCOPE_AGENT);
            } while ((f >> 32) == 0ULL);
            ex += (int)(unsigned)f;
            if ((f >> 32) == 2ULL) break;
        }
        __hip_atomic_store(&flags[b], (2ULL << 32) | (unsigned)(ex + total),
                           __ATOMIC_RELEASE, __HIP_MEMORY_SCOPE_AGENT);
        ex_sh = ex;
    }
    __syncthreads();
    if (i < N_TASK) {
        int st = ex_sh + incl - v;
        start[i] = st;
        cursor[i] = st;
    }
}

// ---- sort scatter: (src, eid) into dst-sorted order (8 B random writes) ----
__global__ __launch_bounds__(256) void scatter_sort(
    const int* __restrict__ src, const int* __restrict__ dst,
    int* __restrict__ cursor, int2* __restrict__ sedge)
{
    int e = blockIdx.x * blockDim.x + threadIdx.x;
    if (e >= NE) return;
    int d = dst[e];
    int pos = atomicAdd(&cursor[d], 1);
    sedge[pos] = make_int2(src[e], e);
}

// ---- fused GAT + softmax + residual + LayerNorm + concat -------------------
// one wave per task node; lane l: channels (2l,2l+1) i.e. cols 2l,2l+1 of [H*C]
__global__ __launch_bounds__(256) void node_gat(
    const unsigned* __restrict__ xlb, const unsigned* __restrict__ xrb,
    const uint4* __restrict__ eaf, const unsigned* __restrict__ Wp,
    const float* __restrict__ att,
    const int* __restrict__ seg_start, const int* __restrict__ seg_cnt,
    const int2* __restrict__ sedge,
    const float* __restrict__ tx, const float* __restrict__ Wres,
    const float* __restrict__ bias, const float* __restrict__ g,
    const float* __restrict__ beta, float* __restrict__ out)
{
    __shared__ float Ws[64 * 64];
    for (int i = threadIdx.x; i < 64 * 64; i += 256) Ws[i] = Wres[i];
    __syncthreads();

    int wv = threadIdx.x >> 6;
    int lane = threadIdx.x & 63;
    int li = lane & 31;
    int n = blockIdx.x * 4 + wv;
    if (n >= N_TASK) return;

    // W_e k-pair fragments for this lane's two columns
    const uint2* Wp2 = (const uint2*)Wp;
    uint2 wp0 = Wp2[0 * 64 + lane], wp1 = Wp2[1 * 64 + lane];
    uint2 wp2 = Wp2[2 * 64 + lane], wp3 = Wp2[3 * 64 + lane];
    uint2 wp4 = Wp2[4 * 64 + lane], wp5 = Wp2[5 * 64 + lane];
    uint2 wp6 = Wp2[6 * 64 + lane], wp7 = Wp2[7 * 64 + lane];

    unsigned xru = xrb[(size_t)n * 64 + lane];
    float xr0 = f16_lo(xru), xr1 = f16_hi(xru);
    float2 at = *(const float2*)(att + lane * 2);

    int beg = __builtin_amdgcn_readfirstlane(seg_start[n]);
    int cnt = __builtin_amdgcn_readfirstlane(seg_cnt[n]);

    float acc0 = 0.f, acc1 = 0.f, den = 0.f;

    // pre-lrelu-dot for one edge; also returns decoded x_l pair
    auto palpha = [&](unsigned xu, uint4 u0, uint4 u1, float& xx, float& xy) {
        float ev0 = 0.f, ev1 = 0.f;
        ev0 = fdot2f(u0.x, wp0.x, ev0); ev1 = fdot2f(u0.x, wp0.y, ev1);
        ev0 = fdot2f(u0.y, wp1.x, ev0); ev1 = fdot2f(u0.y, wp1.y, ev1);
        ev0 = fdot2f(u0.z, wp2.x, ev0); ev1 = fdot2f(u0.z, wp2.y, ev1);
        ev0 = fdot2f(u0.w, wp3.x, ev0); ev1 = fdot2f(u0.w, wp3.y, ev1);
        ev0 = fdot2f(u1.x, wp4.x, ev0); ev1 = fdot2f(u1.x, wp4.y, ev1);
        ev0 = fdot2f(u1.y, wp5.x, ev0); ev1 = fdot2f(u1.y, wp5.y, ev1);
        ev0 = fdot2f(u1.z, wp6.x, ev0); ev1 = fdot2f(u1.z, wp6.y, ev1);
        ev0 = fdot2f(u1.w, wp7.x, ev0); ev1 = fdot2f(u1.w, wp7.y, ev1);
        xx = f16_lo(xu); xy = f16_hi(xu);
        float v0 = xx + xr0 + ev0; v0 = v0 > 0.f ? v0 : 0.2f * v0;
        float v1 = xy + xr1 + ev1; v1 = v1 > 0.f ? v1 : 0.2f * v1;
        return v0 * at.x + v1 * at.y;
    };

#define PAYLOAD(se, xu, e0, e1) do {                                         \
    int s_ = __builtin_amdgcn_readfirstlane((se).x);                         \
    int e_ = __builtin_amdgcn_readfirstlane((se).y);                         \
    xu = xlb[(size_t)s_ * 64 + lane];                                        \
    const uint4* p_ = eaf + (size_t)e_ * 2;                                  \
    e0 = p_[0]; e1 = p_[1];                                                  \
} while (0)

    // depth-2 payload slots + depth-4 index prefetch
    int2 se0 = {0, 0}, se1 = {0, 0};
    unsigned xuA = 0, xuB = 0;
    uint4 A0 = {0,0,0,0}, A1 = {0,0,0,0}, B0 = {0,0,0,0}, B1 = {0,0,0,0};
    if (cnt > 0) se0 = sedge[beg];
    if (cnt > 1) se1 = sedge[beg + 1];
    if (cnt > 0) PAYLOAD(se0, xuA, A0, A1);
    if (cnt > 1) PAYLOAD(se1, xuB, B0, B1);
    if (cnt > 2) se0 = sedge[beg + 2];
    if (cnt > 3) se1 = sedge[beg + 3];

    int i = 0;
    for (; i + 2 <= cnt; i += 2) {
        float xax, xay, xbx, xby;
        float pA = palpha(xuA, A0, A1, xax, xay);
        float pB = palpha(xuB, B0, B1, xbx, xby);
        if (i + 2 < cnt) PAYLOAD(se0, xuA, A0, A1);
        if (i + 3 < cnt) PAYLOAD(se1, xuB, B0, B1);
        if (i + 4 < cnt) se0 = sedge[beg + i + 4];
        if (i + 5 < cnt) se1 = sedge[beg + i + 5];
#pragma unroll
        for (int m = 1; m <= 16; m <<= 1) {
            pA += __shfl_xor(pA, m);
            pB += __shfl_xor(pB, m);
        }
        float wA = __expf(pA), wB = __expf(pB);
        den  += wA + wB;
        acc0 += wA * xax + wB * xbx;
        acc1 += wA * xay + wB * xby;
    }
    if (i < cnt) {   // odd leftover sits in slot A
        float xax, xay;
        float p = palpha(xuA, A0, A1, xax, xay);
#pragma unroll
        for (int m = 1; m <= 16; m <<= 1) p += __shfl_xor(p, m);
        float w = __expf(p);
        den += w; acc0 += w * xax; acc1 += w * xay;
    }
#undef PAYLOAD

    float inv = 1.f / (den + 1e-16f);        // cnt==0 -> acc=0 -> matches ref
    float o0 = acc0 * inv, o1 = acc1 * inv;

    // head mean across the two 32-lane halves
    float m0 = 0.5f * (o0 + __shfl_xor(o0, 32));
    float m1 = 0.5f * (o1 + __shfl_xor(o1, 32));

    // residual GEMV
    const float* txr = tx + (size_t)n * 64;
    float r0 = 0.f, r1 = 0.f;
#pragma unroll 8
    for (int k = 0; k < 64; ++k) {
        float t = txr[k];
        float2 w2 = *(const float2*)(Ws + k * 64 + li * 2);
        r0 += t * w2.x; r1 += t * w2.y;
    }
    float o0f = m0 + r0 + bias[li * 2];
    float o1f = m1 + r1 + bias[li * 2 + 1];

    // LayerNorm over 64 channels (2/lane across each 32-lane half)
    float sum = o0f + o1f, ssq = o0f * o0f + o1f * o1f;
#pragma unroll
    for (int m = 1; m <= 16; m <<= 1) {
        sum += __shfl_xor(sum, m);
        ssq += __shfl_xor(ssq, m);
    }
    float mu = sum * (1.f / 64.f);
    float var = ssq * (1.f / 64.f) - mu * mu;
    float is = rsqrtf(var + 1e-5f);
    float x0o = (o0f - mu) * is * g[li * 2]     + beta[li * 2];
    float x1o = (o1f - mu) * is * g[li * 2 + 1] + beta[li * 2 + 1];
    x0o = x0o > 0.f ? x0o : 0.01f * x0o;
    x1o = x1o > 0.f ? x1o : 0.01f * x1o;

    if (lane < 32) {
        float2 o = {x0o, x1o};
        *(float2*)(out + (size_t)n * 128 + li * 2) = o;
    } else {
        float2 t2 = *(const float2*)(txr + li * 2);
        *(float2*)(out + (size_t)n * 128 + 64 + li * 2) = t2;
    }
}

extern "C" void kernel_launch(void* const* d_in, const int* in_sizes, int n_in,
                              void* d_out, int out_size, void* d_ws, size_t ws_size,
                              hipStream_t stream)
{
    const float* task_x    = (const float*)d_in[0];
    const float* data_x    = (const float*)d_in[1];
    const float* edge_attr = (const float*)d_in[2];
    const int*   src_idx   = (const int*)d_in[3];
    const int*   dst_idx   = (const int*)d_in[4];
    const float* W_l       = (const float*)d_in[5];
    const float* b_l       = (const float*)d_in[6];
    const float* W_r       = (const float*)d_in[7];
    const float* b_r       = (const float*)d_in[8];
    const float* W_e       = (const float*)d_in[9];
    const float* att       = (const float*)d_in[10];
    const float* W_res     = (const float*)d_in[11];
    const float* conv_bias = (const float*)d_in[12];
    const float* ln_g      = (const float*)d_in[13];
    const float* ln_b      = (const float*)d_in[14];
    float* out = (float*)d_out;

    // workspace layout (~99.7 MB)
    unsigned* xlb  = (unsigned*)d_ws;                  // 3,200,000 u32 (x_l f16)
    unsigned* xrb  = xlb + 3200000;                    // 6,400,000 u32 (x_r f16)
    uint4*    eaf  = (uint4*)(xrb + 6400000);          // 3,000,000 uint4 (ea f16)
    unsigned* Wp   = (unsigned*)(eaf + 3000000);       // 1,024 (W_e k-pairs)
    int*      hist = (int*)(Wp + 1024);                // 100,000
    unsigned long long* flags = (unsigned long long*)(hist + 100000); // 128
    int*     start = (int*)(flags + 128);              // 100,000
    int*    cursor = start + 100000;                   // 100,000
    int2*    sedge = (int2*)(cursor + 100000);         // 1,500,000 int2

    // zero hist + flags (stream-ordered, graph-capturable)
    hipMemsetAsync(hist, 0, 100000 * sizeof(int) + 128 * sizeof(unsigned long long),
                   stream);
    gemm_pre     <<<37501, 256, 0, stream>>>(data_x, W_l, b_l, task_x, W_r, b_r,
                                             W_e, xlb, xrb, Wp);
    ea_pack      <<<23438, 256, 0, stream>>>((const float4*)edge_attr, (uint2*)eaf);
    hist_k       <<<1465, 256, 0, stream>>>((const int4*)dst_idx, hist);
    scan_lookback<<<NB_SCAN, SCAN_B, 0, stream>>>(hist, flags, start, cursor);
    scatter_sort <<<5860, 256, 0, stream>>>(src_idx, dst_idx, cursor, sedge);
    node_gat     <<<25000, 256, 0, stream>>>(xlb, xrb, eaf, Wp, att,
                                             start, hist, sedge,
                                             task_x, W_res, conv_bias, ln_g, ln_b, out);
}

// Round 7
// 488.690 us; speedup vs baseline: 1.4442x; 1.4442x over previous
//
#include <hip/hip_runtime.h>
#include <hip/hip_bf16.h>

#define N_TASK 100000
#define N_DATA 50000
#define NE     1500000
// D_TASK = D_DATA = 64, D_EDGE = 16, H = 2, C = 64, H*C = 128
#define SCAN_B 1024
#define NB_SCAN 98   // ceil(100000/1024)

typedef _Float16 half2v __attribute__((ext_vector_type(2)));

__device__ __forceinline__ unsigned pack_f16(float a, float b) {
    half2v h = {(_Float16)a, (_Float16)b};
    return __builtin_bit_cast(unsigned, h);
}
__device__ __forceinline__ float f16_lo(unsigned u) {
    half2v h = __builtin_bit_cast(half2v, u); return (float)h.x;
}
__device__ __forceinline__ float f16_hi(unsigned u) {
    half2v h = __builtin_bit_cast(half2v, u); return (float)h.y;
}
// f32 += f16x2 . f16x2 (v_dot2_f32_f16), with scalar fallback
__device__ __forceinline__ float fdot2f(unsigned a, unsigned b, float c) {
#if __has_builtin(__builtin_amdgcn_fdot2)
    return __builtin_amdgcn_fdot2(__builtin_bit_cast(half2v, a),
                                  __builtin_bit_cast(half2v, b), c, false);
#else
    return c + f16_lo(a) * f16_lo(b) + f16_hi(a) * f16_hi(b);
#endif
}

// ---- register-tiled GEMM: 64 rows/block, 16 rows/wave, W amortized 16x -----
// Y[N,128] = X[N,64] @ W[64,128] + b, output packed f16 pairs.
__device__ __forceinline__ void gemm_tile64(
    const float* __restrict__ X, const float* __restrict__ W,
    const float* __restrict__ bias, unsigned* __restrict__ Yp,
    int nrows, int tb, float* Xs /* [64*64] */)
{
    int row0 = tb * 64;
    const float4* X4 = (const float4*)(X + (size_t)row0 * 64);
    float4* Xs4 = (float4*)Xs;
#pragma unroll
    for (int gi = 0; gi < 4; ++gi) {                 // stage 64x64 f32, coalesced
        int g = threadIdx.x + gi * 256;
        float4 v = {0.f, 0.f, 0.f, 0.f};
        if (row0 + (g >> 4) < nrows) v = X4[g];
        Xs4[g] = v;
    }
    __syncthreads();
    int wv = threadIdx.x >> 6, lane = threadIdx.x & 63;
    const float* Xw = Xs + (wv * 16) * 64;           // this wave's 16 rows
    float2 bb = *(const float2*)(bias + lane * 2);
    float2 acc[16];
#pragma unroll
    for (int r = 0; r < 16; ++r) acc[r] = bb;
#pragma unroll 4
    for (int k4 = 0; k4 < 16; ++k4) {
        float2 w0 = *(const float2*)(W + (k4 * 4 + 0) * 128 + lane * 2);
        float2 w1 = *(const float2*)(W + (k4 * 4 + 1) * 128 + lane * 2);
        float2 w2 = *(const float2*)(W + (k4 * 4 + 2) * 128 + lane * 2);
        float2 w3 = *(const float2*)(W + (k4 * 4 + 3) * 128 + lane * 2);
#pragma unroll
        for (int r = 0; r < 16; ++r) {
            float4 xv = *(const float4*)(Xw + r * 64 + k4 * 4);  // LDS broadcast
            acc[r].x += xv.x * w0.x + xv.y * w1.x + xv.z * w2.x + xv.w * w3.x;
            acc[r].y += xv.x * w0.y + xv.y * w1.y + xv.z * w2.y + xv.w * w3.y;
        }
    }
#pragma unroll
    for (int r = 0; r < 16; ++r) {
        int row = row0 + wv * 16 + r;
        if (row < nrows) Yp[(size_t)row * 64 + lane] = pack_f16(acc[r].x, acc[r].y);
    }
}

// blocks [0,782): x_l tiles; [782,2345): x_r tiles; block 2345: pack W_e
__global__ __launch_bounds__(256) void gemm_pre(
    const float* __restrict__ data_x, const float* __restrict__ Wl,
    const float* __restrict__ bl,
    const float* __restrict__ task_x, const float* __restrict__ Wr,
    const float* __restrict__ br,
    const float* __restrict__ We,
    unsigned* __restrict__ xlb, unsigned* __restrict__ xrb,
    unsigned* __restrict__ Wp)
{
    __shared__ float Xs[64 * 64];
    int b = blockIdx.x;
    if (b < 782) {
        gemm_tile64(data_x, Wl, bl, xlb, N_DATA, b, Xs);
    } else if (b < 2345) {
        gemm_tile64(task_x, Wr, br, xrb, N_TASK, b - 782, Xs);
    } else {
#pragma unroll
        for (int r = 0; r < 4; ++r) {
            int idx = threadIdx.x * 4 + r;          // kp*128 + col
            int kp = idx >> 7, col = idx & 127;
            Wp[idx] = pack_f16(We[(2 * kp) * 128 + col],
                               We[(2 * kp + 1) * 128 + col]);
        }
    }
}

// ---- edge_attr -> f16 pairs, fully coalesced linear copy -------------------
__global__ __launch_bounds__(256) void ea_pack(
    const float4* __restrict__ ea4, uint2* __restrict__ eafu2)
{
    int g = blockIdx.x * blockDim.x + threadIdx.x;
    if (g >= NE * 4) return;                 // NE*16 floats / 4
    float4 q = ea4[g];
    uint2 o;
    o.x = pack_f16(q.x, q.y);
    o.y = pack_f16(q.z, q.w);
    eafu2[g] = o;
}

// ---- dst histogram: 4 edges/thread, coalesced int4 reads -------------------
__global__ __launch_bounds__(256) void hist_k(
    const int4* __restrict__ dst4, int* __restrict__ hist)
{
    int g = blockIdx.x * blockDim.x + threadIdx.x;
    if (g >= NE / 4) return;
    int4 d = dst4[g];
    atomicAdd(&hist[d.x], 1);
    atomicAdd(&hist[d.y], 1);
    atomicAdd(&hist[d.z], 1);
    atomicAdd(&hist[d.w], 1);
}

// ---- single-kernel decoupled-lookback exclusive scan -----------------------
__global__ __launch_bounds__(SCAN_B) void scan_lookback(
    const int* __restrict__ hist, unsigned long long* __restrict__ flags,
    int* __restrict__ start, int* __restrict__ cursor)
{
    __shared__ int s[SCAN_B];
    __shared__ int ex_sh;
    int tid = threadIdx.x, b = blockIdx.x;
    int i = b * SCAN_B + tid;
    int v = (i < N_TASK) ? hist[i] : 0;
    s[tid] = v;
    __syncthreads();
#pragma unroll
    for (int off = 1; off < SCAN_B; off <<= 1) {
        int t = (tid >= off) ? s[tid - off] : 0;
        __syncthreads();
        s[tid] += t;
        __syncthreads();
    }
    int incl = s[tid];
    if (tid == 0) {
        int total = s[SCAN_B - 1];
        __hip_atomic_store(&flags[b], (1ULL << 32) | (unsigned)total,
                           __ATOMIC_RELEASE, __HIP_MEMORY_SCOPE_AGENT);
        int ex = 0;
        for (int p = b - 1; p >= 0; --p) {
            unsigned long long f;
            do {
                f = __hip_atomic_load(&flags[p], __ATOMIC_ACQUIRE,
                                      __HIP_MEMORY_SCOPE_AGENT);
            } while ((f >> 32) == 0ULL);
            ex += (int)(unsigned)f;
            if ((f >> 32) == 2ULL) break;
        }
        __hip_atomic_store(&flags[b], (2ULL << 32) | (unsigned)(ex + total),
                           __ATOMIC_RELEASE, __HIP_MEMORY_SCOPE_AGENT);
        ex_sh = ex;
    }
    __syncthreads();
    if (i < N_TASK) {
        int st = ex_sh + incl - v;
        start[i] = st;
        cursor[i] = st;
    }
}

// ---- sort scatter: (src, eid) into dst-sorted order (8 B random writes) ----
__global__ __launch_bounds__(256) void scatter_sort(
    const int* __restrict__ src, const int* __restrict__ dst,
    int* __restrict__ cursor, int2* __restrict__ sedge)
{
    int e = blockIdx.x * blockDim.x + threadIdx.x;
    if (e >= NE) return;
    int d = dst[e];
    int pos = atomicAdd(&cursor[d], 1);
    sedge[pos] = make_int2(src[e], e);
}

// ---- fused GAT + softmax + residual + LayerNorm + concat -------------------
// one wave per task node; lane l: channels (2l,2l+1) i.e. cols 2l,2l+1 of [H*C]
__global__ __launch_bounds__(256) void node_gat(
    const unsigned* __restrict__ xlb, const unsigned* __restrict__ xrb,
    const uint4* __restrict__ eaf, const unsigned* __restrict__ Wp,
    const float* __restrict__ att,
    const int* __restrict__ seg_start, const int* __restrict__ seg_cnt,
    const int2* __restrict__ sedge,
    const float* __restrict__ tx, const float* __restrict__ Wres,
    const float* __restrict__ bias, const float* __restrict__ g,
    const float* __restrict__ beta, float* __restrict__ out)
{
    __shared__ float Ws[64 * 64];
    for (int i = threadIdx.x; i < 64 * 64; i += 256) Ws[i] = Wres[i];
    __syncthreads();

    int wv = threadIdx.x >> 6;
    int lane = threadIdx.x & 63;
    int li = lane & 31;
    int n = blockIdx.x * 4 + wv;
    if (n >= N_TASK) return;

    // W_e k-pair fragments for this lane's two columns
    const uint2* Wp2 = (const uint2*)Wp;
    uint2 wp0 = Wp2[0 * 64 + lane], wp1 = Wp2[1 * 64 + lane];
    uint2 wp2 = Wp2[2 * 64 + lane], wp3 = Wp2[3 * 64 + lane];
    uint2 wp4 = Wp2[4 * 64 + lane], wp5 = Wp2[5 * 64 + lane];
    uint2 wp6 = Wp2[6 * 64 + lane], wp7 = Wp2[7 * 64 + lane];

    unsigned xru = xrb[(size_t)n * 64 + lane];
    float xr0 = f16_lo(xru), xr1 = f16_hi(xru);
    float2 at = *(const float2*)(att + lane * 2);

    int beg = __builtin_amdgcn_readfirstlane(seg_start[n]);
    int cnt = __builtin_amdgcn_readfirstlane(seg_cnt[n]);

    float acc0 = 0.f, acc1 = 0.f, den = 0.f;

    // pre-lrelu-dot for one edge; also returns decoded x_l pair
    auto palpha = [&](unsigned xu, uint4 u0, uint4 u1, float& xx, float& xy) {
        float ev0 = 0.f, ev1 = 0.f;
        ev0 = fdot2f(u0.x, wp0.x, ev0); ev1 = fdot2f(u0.x, wp0.y, ev1);
        ev0 = fdot2f(u0.y, wp1.x, ev0); ev1 = fdot2f(u0.y, wp1.y, ev1);
        ev0 = fdot2f(u0.z, wp2.x, ev0); ev1 = fdot2f(u0.z, wp2.y, ev1);
        ev0 = fdot2f(u0.w, wp3.x, ev0); ev1 = fdot2f(u0.w, wp3.y, ev1);
        ev0 = fdot2f(u1.x, wp4.x, ev0); ev1 = fdot2f(u1.x, wp4.y, ev1);
        ev0 = fdot2f(u1.y, wp5.x, ev0); ev1 = fdot2f(u1.y, wp5.y, ev1);
        ev0 = fdot2f(u1.z, wp6.x, ev0); ev1 = fdot2f(u1.z, wp6.y, ev1);
        ev0 = fdot2f(u1.w, wp7.x, ev0); ev1 = fdot2f(u1.w, wp7.y, ev1);
        xx = f16_lo(xu); xy = f16_hi(xu);
        float v0 = xx + xr0 + ev0; v0 = v0 > 0.f ? v0 : 0.2f * v0;
        float v1 = xy + xr1 + ev1; v1 = v1 > 0.f ? v1 : 0.2f * v1;
        return v0 * at.x + v1 * at.y;
    };

#define PAYLOAD(se, xu, e0, e1) do {                                         \
    int s_ = __builtin_amdgcn_readfirstlane((se).x);                         \
    int e_ = __builtin_amdgcn_readfirstlane((se).y);                         \
    xu = xlb[(size_t)s_ * 64 + lane];                                        \
    const uint4* p_ = eaf + (size_t)e_ * 2;                                  \
    e0 = p_[0]; e1 = p_[1];                                                  \
} while (0)

    // depth-2 payload slots + depth-4 index prefetch
    int2 se0 = {0, 0}, se1 = {0, 0};
    unsigned xuA = 0, xuB = 0;
    uint4 A0 = {0,0,0,0}, A1 = {0,0,0,0}, B0 = {0,0,0,0}, B1 = {0,0,0,0};
    if (cnt > 0) se0 = sedge[beg];
    if (cnt > 1) se1 = sedge[beg + 1];
    if (cnt > 0) PAYLOAD(se0, xuA, A0, A1);
    if (cnt > 1) PAYLOAD(se1, xuB, B0, B1);
    if (cnt > 2) se0 = sedge[beg + 2];
    if (cnt > 3) se1 = sedge[beg + 3];

    int i = 0;
    for (; i + 2 <= cnt; i += 2) {
        float xax, xay, xbx, xby;
        float pA = palpha(xuA, A0, A1, xax, xay);
        float pB = palpha(xuB, B0, B1, xbx, xby);
        if (i + 2 < cnt) PAYLOAD(se0, xuA, A0, A1);
        if (i + 3 < cnt) PAYLOAD(se1, xuB, B0, B1);
        if (i + 4 < cnt) se0 = sedge[beg + i + 4];
        if (i + 5 < cnt) se1 = sedge[beg + i + 5];
#pragma unroll
        for (int m = 1; m <= 16; m <<= 1) {
            pA += __shfl_xor(pA, m);
            pB += __shfl_xor(pB, m);
        }
        float wA = __expf(pA), wB = __expf(pB);
        den  += wA + wB;
        acc0 += wA * xax + wB * xbx;
        acc1 += wA * xay + wB * xby;
    }
    if (i < cnt) {   // odd leftover sits in slot A
        float xax, xay;
        float p = palpha(xuA, A0, A1, xax, xay);
#pragma unroll
        for (int m = 1; m <= 16; m <<= 1) p += __shfl_xor(p, m);
        float w = __expf(p);
        den += w; acc0 += w * xax; acc1 += w * xay;
    }
#undef PAYLOAD

    float inv = 1.f / (den + 1e-16f);        // cnt==0 -> acc=0 -> matches ref
    float o0 = acc0 * inv, o1 = acc1 * inv;

    // head mean across the two 32-lane halves
    float m0 = 0.5f * (o0 + __shfl_xor(o0, 32));
    float m1 = 0.5f * (o1 + __shfl_xor(o1, 32));

    // residual GEMV
    const float* txr = tx + (size_t)n * 64;
    float r0 = 0.f, r1 = 0.f;
#pragma unroll 8
    for (int k = 0; k < 64; ++k) {
        float t = txr[k];
        float2 w2 = *(const float2*)(Ws + k * 64 + li * 2);
        r0 += t * w2.x; r1 += t * w2.y;
    }
    float o0f = m0 + r0 + bias[li * 2];
    float o1f = m1 + r1 + bias[li * 2 + 1];

    // LayerNorm over 64 channels (2/lane across each 32-lane half)
    float sum = o0f + o1f, ssq = o0f * o0f + o1f * o1f;
#pragma unroll
    for (int m = 1; m <= 16; m <<= 1) {
        sum += __shfl_xor(sum, m);
        ssq += __shfl_xor(ssq, m);
    }
    float mu = sum * (1.f / 64.f);
    float var = ssq * (1.f / 64.f) - mu * mu;
    float is = rsqrtf(var + 1e-5f);
    float x0o = (o0f - mu) * is * g[li * 2]     + beta[li * 2];
    float x1o = (o1f - mu) * is * g[li * 2 + 1] + beta[li * 2 + 1];
    x0o = x0o > 0.f ? x0o : 0.01f * x0o;
    x1o = x1o > 0.f ? x1o : 0.01f * x1o;

    if (lane < 32) {
        float2 o = {x0o, x1o};
        *(float2*)(out + (size_t)n * 128 + li * 2) = o;
    } else {
        float2 t2 = *(const float2*)(txr + li * 2);
        *(float2*)(out + (size_t)n * 128 + 64 + li * 2) = t2;
    }
}

extern "C" void kernel_launch(void* const* d_in, const int* in_sizes, int n_in,
                              void* d_out, int out_size, void* d_ws, size_t ws_size,
                              hipStream_t stream)
{
    const float* task_x    = (const float*)d_in[0];
    const float* data_x    = (const float*)d_in[1];
    const float* edge_attr = (const float*)d_in[2];
    const int*   src_idx   = (const int*)d_in[3];
    const int*   dst_idx   = (const int*)d_in[4];
    const float* W_l       = (const float*)d_in[5];
    const float* b_l       = (const float*)d_in[6];
    const float* W_r       = (const float*)d_in[7];
    const float* b_r       = (const float*)d_in[8];
    const float* W_e       = (const float*)d_in[9];
    const float* att       = (const float*)d_in[10];
    const float* W_res     = (const float*)d_in[11];
    const float* conv_bias = (const float*)d_in[12];
    const float* ln_g      = (const float*)d_in[13];
    const float* ln_b      = (const float*)d_in[14];
    float* out = (float*)d_out;

    // workspace layout (~99.7 MB)
    unsigned* xlb  = (unsigned*)d_ws;                  // 3,200,000 u32 (x_l f16)
    unsigned* xrb  = xlb + 3200000;                    // 6,400,000 u32 (x_r f16)
    uint4*    eaf  = (uint4*)(xrb + 6400000);          // 3,000,000 uint4 (ea f16)
    unsigned* Wp   = (unsigned*)(eaf + 3000000);       // 1,024 (W_e k-pairs)
    int*      hist = (int*)(Wp + 1024);                // 100,000
    unsigned long long* flags = (unsigned long long*)(hist + 100000); // 128
    int*     start = (int*)(flags + 128);              // 100,000
    int*    cursor = start + 100000;                   // 100,000
    int2*    sedge = (int2*)(cursor + 100000);         // 1,500,000 int2

    // zero hist + flags (stream-ordered, graph-capturable)
    hipMemsetAsync(hist, 0, 100000 * sizeof(int) + 128 * sizeof(unsigned long long),
                   stream);
    gemm_pre     <<<2346, 256, 0, stream>>>(data_x, W_l, b_l, task_x, W_r, b_r,
                                            W_e, xlb, xrb, Wp);
    ea_pack      <<<23438, 256, 0, stream>>>((const float4*)edge_attr, (uint2*)eaf);
    hist_k       <<<1465, 256, 0, stream>>>((const int4*)dst_idx, hist);
    scan_lookback<<<NB_SCAN, SCAN_B, 0, stream>>>(hist, flags, start, cursor);
    scatter_sort <<<5860, 256, 0, stream>>>(src_idx, dst_idx, cursor, sedge);
    node_gat     <<<25000, 256, 0, stream>>>(xlb, xrb, eaf, Wp, att,
                                             start, hist, sedge,
                                             task_x, W_res, conv_bias, ln_g, ln_b, out);
}

// Round 8
// 428.497 us; speedup vs baseline: 1.6471x; 1.1405x over previous
//
#include <hip/hip_runtime.h>
#include <hip/hip_bf16.h>

#define N_TASK 100000
#define N_DATA 50000
#define NE     1500000
// D_TASK = D_DATA = 64, D_EDGE = 16, H = 2, C = 64, H*C = 128
#define SCAN_B 1024
#define NB_SCAN 98   // ceil(100000/1024)

typedef _Float16 half2v __attribute__((ext_vector_type(2)));

__device__ __forceinline__ unsigned pack_f16(float a, float b) {
    half2v h = {(_Float16)a, (_Float16)b};
    return __builtin_bit_cast(unsigned, h);
}
__device__ __forceinline__ float f16_lo(unsigned u) {
    half2v h = __builtin_bit_cast(half2v, u); return (float)h.x;
}
__device__ __forceinline__ float f16_hi(unsigned u) {
    half2v h = __builtin_bit_cast(half2v, u); return (float)h.y;
}
// f32 += f16x2 . f16x2 (v_dot2_f32_f16), with scalar fallback
__device__ __forceinline__ float fdot2f(unsigned a, unsigned b, float c) {
#if __has_builtin(__builtin_amdgcn_fdot2)
    return __builtin_amdgcn_fdot2(__builtin_bit_cast(half2v, a),
                                  __builtin_bit_cast(half2v, b), c, false);
#else
    return c + f16_lo(a) * f16_lo(b) + f16_hi(a) * f16_hi(b);
#endif
}

// ---- register-tiled GEMM: 64 rows/block, 16 rows/wave, W amortized 16x -----
// Y[N,128] = X[N,64] @ W[64,128] + b, output packed f16 pairs.
__device__ __forceinline__ void gemm_tile64(
    const float* __restrict__ X, const float* __restrict__ W,
    const float* __restrict__ bias, unsigned* __restrict__ Yp,
    int nrows, int tb, float* Xs /* [64*64] */)
{
    int row0 = tb * 64;
    const float4* X4 = (const float4*)(X + (size_t)row0 * 64);
    float4* Xs4 = (float4*)Xs;
#pragma unroll
    for (int gi = 0; gi < 4; ++gi) {                 // stage 64x64 f32, coalesced
        int g = threadIdx.x + gi * 256;
        float4 v = {0.f, 0.f, 0.f, 0.f};
        if (row0 + (g >> 4) < nrows) v = X4[g];
        Xs4[g] = v;
    }
    __syncthreads();
    int wv = threadIdx.x >> 6, lane = threadIdx.x & 63;
    const float* Xw = Xs + (wv * 16) * 64;           // this wave's 16 rows
    float2 bb = *(const float2*)(bias + lane * 2);
    float2 acc[16];
#pragma unroll
    for (int r = 0; r < 16; ++r) acc[r] = bb;
#pragma unroll 4
    for (int k4 = 0; k4 < 16; ++k4) {
        float2 w0 = *(const float2*)(W + (k4 * 4 + 0) * 128 + lane * 2);
        float2 w1 = *(const float2*)(W + (k4 * 4 + 1) * 128 + lane * 2);
        float2 w2 = *(const float2*)(W + (k4 * 4 + 2) * 128 + lane * 2);
        float2 w3 = *(const float2*)(W + (k4 * 4 + 3) * 128 + lane * 2);
#pragma unroll
        for (int r = 0; r < 16; ++r) {
            float4 xv = *(const float4*)(Xw + r * 64 + k4 * 4);  // LDS broadcast
            acc[r].x += xv.x * w0.x + xv.y * w1.x + xv.z * w2.x + xv.w * w3.x;
            acc[r].y += xv.x * w0.y + xv.y * w1.y + xv.z * w2.y + xv.w * w3.y;
        }
    }
#pragma unroll
    for (int r = 0; r < 16; ++r) {
        int row = row0 + wv * 16 + r;
        if (row < nrows) Yp[(size_t)row * 64 + lane] = pack_f16(acc[r].x, acc[r].y);
    }
}

// residual GEMM: Y[N,64] = X[N,64] @ W[64,64], f32 out (no bias)
__device__ __forceinline__ void gemm_tile64_res(
    const float* __restrict__ X, const float* __restrict__ W,
    float* __restrict__ Y, int nrows, int tb, float* Xs)
{
    int row0 = tb * 64;
    const float4* X4 = (const float4*)(X + (size_t)row0 * 64);
    float4* Xs4 = (float4*)Xs;
#pragma unroll
    for (int gi = 0; gi < 4; ++gi) {
        int g = threadIdx.x + gi * 256;
        float4 v = {0.f, 0.f, 0.f, 0.f};
        if (row0 + (g >> 4) < nrows) v = X4[g];
        Xs4[g] = v;
    }
    __syncthreads();
    int wv = threadIdx.x >> 6, lane = threadIdx.x & 63;  // lane = output col
    const float* Xw = Xs + (wv * 16) * 64;
    float acc[16];
#pragma unroll
    for (int r = 0; r < 16; ++r) acc[r] = 0.f;
#pragma unroll 4
    for (int k4 = 0; k4 < 16; ++k4) {
        float w0 = W[(k4 * 4 + 0) * 64 + lane];
        float w1 = W[(k4 * 4 + 1) * 64 + lane];
        float w2 = W[(k4 * 4 + 2) * 64 + lane];
        float w3 = W[(k4 * 4 + 3) * 64 + lane];
#pragma unroll
        for (int r = 0; r < 16; ++r) {
            float4 xv = *(const float4*)(Xw + r * 64 + k4 * 4);
            acc[r] += xv.x * w0 + xv.y * w1 + xv.z * w2 + xv.w * w3;
        }
    }
#pragma unroll
    for (int r = 0; r < 16; ++r) {
        int row = row0 + wv * 16 + r;
        if (row < nrows) Y[(size_t)row * 64 + lane] = acc[r];
    }
}

// ---- fused prologue: all GAT-independent work, block-range dispatched ------
// [0,23438):       ea -> f16 pairs (coalesced linear)
// [23438,24220):   x_l gemm tiles (782)
// [24220,25783):   x_r gemm tiles (1563)
// [25783,27346):   res gemm tiles (1563)
// [27346,28811):   dst histogram (1465)
// [28811,35061):   concat copy out[:,64:] = task_x (6250)
// [35061]:         pack W_e k-pairs
#define FP_EA0   0
#define FP_XL0   23438
#define FP_XR0   24220
#define FP_RES0  25783
#define FP_HIST0 27346
#define FP_CAT0  28811
#define FP_WP    35061
__global__ __launch_bounds__(256) void fused_pre(
    const float* __restrict__ data_x, const float* __restrict__ Wl,
    const float* __restrict__ bl,
    const float* __restrict__ task_x, const float* __restrict__ Wr,
    const float* __restrict__ br,
    const float* __restrict__ Wres, const float* __restrict__ We,
    const float* __restrict__ ea, const int* __restrict__ dst,
    unsigned* __restrict__ xlb, unsigned* __restrict__ xrb,
    float* __restrict__ res, uint2* __restrict__ eafu2,
    unsigned* __restrict__ Wp, int* __restrict__ hist,
    float* __restrict__ out)
{
    __shared__ float Xs[64 * 64];
    int b = blockIdx.x;
    if (b < FP_XL0) {
        int g = b * 256 + threadIdx.x;
        if (g < NE * 4) {
            float4 q = ((const float4*)ea)[g];
            uint2 o;
            o.x = pack_f16(q.x, q.y);
            o.y = pack_f16(q.z, q.w);
            eafu2[g] = o;
        }
    } else if (b < FP_XR0) {
        gemm_tile64(data_x, Wl, bl, xlb, N_DATA, b - FP_XL0, Xs);
    } else if (b < FP_RES0) {
        gemm_tile64(task_x, Wr, br, xrb, N_TASK, b - FP_XR0, Xs);
    } else if (b < FP_HIST0) {
        gemm_tile64_res(task_x, Wres, res, N_TASK, b - FP_RES0, Xs);
    } else if (b < FP_CAT0) {
        int g = (b - FP_HIST0) * 256 + threadIdx.x;
        if (g < NE / 4) {
            int4 d = ((const int4*)dst)[g];
            atomicAdd(&hist[d.x], 1);
            atomicAdd(&hist[d.y], 1);
            atomicAdd(&hist[d.z], 1);
            atomicAdd(&hist[d.w], 1);
        }
    } else if (b < FP_WP) {
        int g = (b - FP_CAT0) * 256 + threadIdx.x;   // float4 idx over [100k,64]
        if (g < N_TASK * 16) {
            int n = g >> 4, c4 = g & 15;
            float4 v = ((const float4*)task_x)[g];
            ((float4*)out)[(size_t)n * 32 + 16 + c4] = v;
        }
    } else {
#pragma unroll
        for (int r = 0; r < 4; ++r) {
            int idx = threadIdx.x * 4 + r;          // kp*128 + col
            int kp = idx >> 7, col = idx & 127;
            Wp[idx] = pack_f16(We[(2 * kp) * 128 + col],
                               We[(2 * kp + 1) * 128 + col]);
        }
    }
}

// ---- single-kernel decoupled-lookback exclusive scan -----------------------
__global__ __launch_bounds__(SCAN_B) void scan_lookback(
    const int* __restrict__ hist, unsigned long long* __restrict__ flags,
    int* __restrict__ start, int* __restrict__ cursor)
{
    __shared__ int s[SCAN_B];
    __shared__ int ex_sh;
    int tid = threadIdx.x, b = blockIdx.x;
    int i = b * SCAN_B + tid;
    int v = (i < N_TASK) ? hist[i] : 0;
    s[tid] = v;
    __syncthreads();
#pragma unroll
    for (int off = 1; off < SCAN_B; off <<= 1) {
        int t = (tid >= off) ? s[tid - off] : 0;
        __syncthreads();
        s[tid] += t;
        __syncthreads();
    }
    int incl = s[tid];
    if (tid == 0) {
        int total = s[SCAN_B - 1];
        __hip_atomic_store(&flags[b], (1ULL << 32) | (unsigned)total,
                           __ATOMIC_RELEASE, __HIP_MEMORY_SCOPE_AGENT);
        int ex = 0;
        for (int p = b - 1; p >= 0; --p) {
            unsigned long long f;
            do {
                f = __hip_atomic_load(&flags[p], __ATOMIC_ACQUIRE,
                                      __HIP_MEMORY_SCOPE_AGENT);
            } while ((f >> 32) == 0ULL);
            ex += (int)(unsigned)f;
            if ((f >> 32) == 2ULL) break;
        }
        __hip_atomic_store(&flags[b], (2ULL << 32) | (unsigned)(ex + total),
                           __ATOMIC_RELEASE, __HIP_MEMORY_SCOPE_AGENT);
        ex_sh = ex;
    }
    __syncthreads();
    if (i < N_TASK) {
        int st = ex_sh + incl - v;
        start[i] = st;
        cursor[i] = st;
    }
}

// ---- sort scatter: (src, eid) into dst-sorted order (8 B random writes) ----
__global__ __launch_bounds__(256) void scatter_sort(
    const int* __restrict__ src, const int* __restrict__ dst,
    int* __restrict__ cursor, int2* __restrict__ sedge)
{
    int e = blockIdx.x * blockDim.x + threadIdx.x;
    if (e >= NE) return;
    int d = dst[e];
    int pos = atomicAdd(&cursor[d], 1);
    sedge[pos] = make_int2(src[e], e);
}

// ---- fused GAT + softmax + (precomputed residual) + LayerNorm --------------
// one wave per task node; lane l: channels (2l,2l+1) i.e. cols 2l,2l+1 of [H*C]
__global__ __launch_bounds__(256) void node_gat(
    const unsigned* __restrict__ xlb, const unsigned* __restrict__ xrb,
    const uint4* __restrict__ eaf, const unsigned* __restrict__ Wp,
    const float* __restrict__ att,
    const int* __restrict__ seg_start, const int* __restrict__ seg_cnt,
    const int2* __restrict__ sedge,
    const float* __restrict__ res, const float* __restrict__ bias,
    const float* __restrict__ g, const float* __restrict__ beta,
    float* __restrict__ out)
{
    int lane = threadIdx.x & 63;
    int li = lane & 31;
    int n = blockIdx.x * 4 + (threadIdx.x >> 6);
    if (n >= N_TASK) return;

    // W_e k-pair fragments for this lane's two columns
    const uint2* Wp2 = (const uint2*)Wp;
    uint2 wp0 = Wp2[0 * 64 + lane], wp1 = Wp2[1 * 64 + lane];
    uint2 wp2 = Wp2[2 * 64 + lane], wp3 = Wp2[3 * 64 + lane];
    uint2 wp4 = Wp2[4 * 64 + lane], wp5 = Wp2[5 * 64 + lane];
    uint2 wp6 = Wp2[6 * 64 + lane], wp7 = Wp2[7 * 64 + lane];

    unsigned xru = xrb[(size_t)n * 64 + lane];
    float xr0 = f16_lo(xru), xr1 = f16_hi(xru);
    float2 at = *(const float2*)(att + lane * 2);

    int beg = __builtin_amdgcn_readfirstlane(seg_start[n]);
    int cnt = __builtin_amdgcn_readfirstlane(seg_cnt[n]);

    float acc0 = 0.f, acc1 = 0.f, den = 0.f;

    // pre-lrelu-dot for one edge; also returns decoded x_l pair
    auto palpha = [&](unsigned xu, uint4 u0, uint4 u1, float& xx, float& xy) {
        float ev0 = 0.f, ev1 = 0.f;
        ev0 = fdot2f(u0.x, wp0.x, ev0); ev1 = fdot2f(u0.x, wp0.y, ev1);
        ev0 = fdot2f(u0.y, wp1.x, ev0); ev1 = fdot2f(u0.y, wp1.y, ev1);
        ev0 = fdot2f(u0.z, wp2.x, ev0); ev1 = fdot2f(u0.z, wp2.y, ev1);
        ev0 = fdot2f(u0.w, wp3.x, ev0); ev1 = fdot2f(u0.w, wp3.y, ev1);
        ev0 = fdot2f(u1.x, wp4.x, ev0); ev1 = fdot2f(u1.x, wp4.y, ev1);
        ev0 = fdot2f(u1.y, wp5.x, ev0); ev1 = fdot2f(u1.y, wp5.y, ev1);
        ev0 = fdot2f(u1.z, wp6.x, ev0); ev1 = fdot2f(u1.z, wp6.y, ev1);
        ev0 = fdot2f(u1.w, wp7.x, ev0); ev1 = fdot2f(u1.w, wp7.y, ev1);
        xx = f16_lo(xu); xy = f16_hi(xu);
        float v0 = xx + xr0 + ev0; v0 = v0 > 0.f ? v0 : 0.2f * v0;
        float v1 = xy + xr1 + ev1; v1 = v1 > 0.f ? v1 : 0.2f * v1;
        return v0 * at.x + v1 * at.y;
    };

#define PAYLOAD(se, xu, e0, e1) do {                                         \
    int s_ = __builtin_amdgcn_readfirstlane((se).x);                         \
    int e_ = __builtin_amdgcn_readfirstlane((se).y);                         \
    xu = xlb[(size_t)s_ * 64 + lane];                                        \
    const uint4* p_ = eaf + (size_t)e_ * 2;                                  \
    e0 = p_[0]; e1 = p_[1];                                                  \
} while (0)

    // depth-2 payload slots + depth-4 index prefetch
    int2 se0 = {0, 0}, se1 = {0, 0};
    unsigned xuA = 0, xuB = 0;
    uint4 A0 = {0,0,0,0}, A1 = {0,0,0,0}, B0 = {0,0,0,0}, B1 = {0,0,0,0};
    if (cnt > 0) se0 = sedge[beg];
    if (cnt > 1) se1 = sedge[beg + 1];
    if (cnt > 0) PAYLOAD(se0, xuA, A0, A1);
    if (cnt > 1) PAYLOAD(se1, xuB, B0, B1);
    if (cnt > 2) se0 = sedge[beg + 2];
    if (cnt > 3) se1 = sedge[beg + 3];

    int i = 0;
    for (; i + 2 <= cnt; i += 2) {
        float xax, xay, xbx, xby;
        float pA = palpha(xuA, A0, A1, xax, xay);
        float pB = palpha(xuB, B0, B1, xbx, xby);
        if (i + 2 < cnt) PAYLOAD(se0, xuA, A0, A1);
        if (i + 3 < cnt) PAYLOAD(se1, xuB, B0, B1);
        if (i + 4 < cnt) se0 = sedge[beg + i + 4];
        if (i + 5 < cnt) se1 = sedge[beg + i + 5];
#pragma unroll
        for (int m = 1; m <= 16; m <<= 1) {
            pA += __shfl_xor(pA, m);
            pB += __shfl_xor(pB, m);
        }
        float wA = __expf(pA), wB = __expf(pB);
        den  += wA + wB;
        acc0 += wA * xax + wB * xbx;
        acc1 += wA * xay + wB * xby;
    }
    if (i < cnt) {   // odd leftover sits in slot A
        float xax, xay;
        float p = palpha(xuA, A0, A1, xax, xay);
#pragma unroll
        for (int m = 1; m <= 16; m <<= 1) p += __shfl_xor(p, m);
        float w = __expf(p);
        den += w; acc0 += w * xax; acc1 += w * xay;
    }
#undef PAYLOAD

    float inv = 1.f / (den + 1e-16f);        // cnt==0 -> acc=0 -> matches ref
    float o0 = acc0 * inv, o1 = acc1 * inv;

    // head mean across the two 32-lane halves
    float m0 = 0.5f * (o0 + __shfl_xor(o0, 32));
    float m1 = 0.5f * (o1 + __shfl_xor(o1, 32));

    // precomputed residual (lanes l and l+32 load the same addr -> broadcast)
    float2 r2 = *(const float2*)(res + (size_t)n * 64 + li * 2);
    float o0f = m0 + r2.x + bias[li * 2];
    float o1f = m1 + r2.y + bias[li * 2 + 1];

    // LayerNorm over 64 channels (2/lane across each 32-lane half)
    float sum = o0f + o1f, ssq = o0f * o0f + o1f * o1f;
#pragma unroll
    for (int m = 1; m <= 16; m <<= 1) {
        sum += __shfl_xor(sum, m);
        ssq += __shfl_xor(ssq, m);
    }
    float mu = sum * (1.f / 64.f);
    float var = ssq * (1.f / 64.f) - mu * mu;
    float is = rsqrtf(var + 1e-5f);
    float x0o = (o0f - mu) * is * g[li * 2]     + beta[li * 2];
    float x1o = (o1f - mu) * is * g[li * 2 + 1] + beta[li * 2 + 1];
    x0o = x0o > 0.f ? x0o : 0.01f * x0o;
    x1o = x1o > 0.f ? x1o : 0.01f * x1o;

    if (lane < 32) {
        float2 o = {x0o, x1o};
        *(float2*)(out + (size_t)n * 128 + li * 2) = o;
    }
    // out[:,64:] (concat of task_x) is written by fused_pre
}

extern "C" void kernel_launch(void* const* d_in, const int* in_sizes, int n_in,
                              void* d_out, int out_size, void* d_ws, size_t ws_size,
                              hipStream_t stream)
{
    const float* task_x    = (const float*)d_in[0];
    const float* data_x    = (const float*)d_in[1];
    const float* edge_attr = (const float*)d_in[2];
    const int*   src_idx   = (const int*)d_in[3];
    const int*   dst_idx   = (const int*)d_in[4];
    const float* W_l       = (const float*)d_in[5];
    const float* b_l       = (const float*)d_in[6];
    const float* W_r       = (const float*)d_in[7];
    const float* b_r       = (const float*)d_in[8];
    const float* W_e       = (const float*)d_in[9];
    const float* att       = (const float*)d_in[10];
    const float* W_res     = (const float*)d_in[11];
    const float* conv_bias = (const float*)d_in[12];
    const float* ln_g      = (const float*)d_in[13];
    const float* ln_b      = (const float*)d_in[14];
    float* out = (float*)d_out;

    // workspace layout (~126 MB)
    unsigned* xlb  = (unsigned*)d_ws;                  // 3,200,000 u32 (x_l f16)
    unsigned* xrb  = xlb + 3200000;                    // 6,400,000 u32 (x_r f16)
    uint4*    eaf  = (uint4*)(xrb + 6400000);          // 3,000,000 uint4 (ea f16)
    float*    res  = (float*)(eaf + 3000000);          // 6,400,000 f (residual)
    unsigned* Wp   = (unsigned*)(res + 6400000);       // 1,024 (W_e k-pairs)
    int*      hist = (int*)(Wp + 1024);                // 100,000
    unsigned long long* flags = (unsigned long long*)(hist + 100000); // 128
    int*     start = (int*)(flags + 128);              // 100,000
    int*    cursor = start + 100000;                   // 100,000
    int2*    sedge = (int2*)(cursor + 100000);         // 1,500,000 int2

    // zero hist + flags (stream-ordered, graph-capturable)
    hipMemsetAsync(hist, 0, 100000 * sizeof(int) + 128 * sizeof(unsigned long long),
                   stream);
    fused_pre    <<<35062, 256, 0, stream>>>(data_x, W_l, b_l, task_x, W_r, b_r,
                                             W_res, W_e, edge_attr, dst_idx,
                                             xlb, xrb, res, (uint2*)eaf, Wp, hist,
                                             out);
    scan_lookback<<<NB_SCAN, SCAN_B, 0, stream>>>(hist, flags, start, cursor);
    scatter_sort <<<5860, 256, 0, stream>>>(src_idx, dst_idx, cursor, sedge);
    node_gat     <<<25000, 256, 0, stream>>>(xlb, xrb, eaf, Wp, att,
                                             start, hist, sedge,
                                             res, conv_bias, ln_g, ln_b, out);
}

// Round 9
// 406.759 us; speedup vs baseline: 1.7351x; 1.0534x over previous
//
#include <hip/hip_runtime.h>
#include <hip/hip_bf16.h>

#define N_TASK 100000
#define N_DATA 50000
#define NE     1500000
// D_TASK = D_DATA = 64, D_EDGE = 16, H = 2, C = 64, H*C = 128
#define SCAN_B 1024
#define NB_SCAN 98   // ceil(100000/1024)

typedef _Float16 half2v __attribute__((ext_vector_type(2)));

__device__ __forceinline__ unsigned pack_f16(float a, float b) {
    half2v h = {(_Float16)a, (_Float16)b};
    return __builtin_bit_cast(unsigned, h);
}
__device__ __forceinline__ float f16_lo(unsigned u) {
    half2v h = __builtin_bit_cast(half2v, u); return (float)h.x;
}
__device__ __forceinline__ float f16_hi(unsigned u) {
    half2v h = __builtin_bit_cast(half2v, u); return (float)h.y;
}
// f32 += f16x2 . f16x2 (v_dot2_f32_f16), with scalar fallback
__device__ __forceinline__ float fdot2f(unsigned a, unsigned b, float c) {
#if __has_builtin(__builtin_amdgcn_fdot2)
    return __builtin_amdgcn_fdot2(__builtin_bit_cast(half2v, a),
                                  __builtin_bit_cast(half2v, b), c, false);
#else
    return c + f16_lo(a) * f16_lo(b) + f16_hi(a) * f16_hi(b);
#endif
}
__device__ __forceinline__ float fdot2h(half2v a, half2v b, float c) {
#if __has_builtin(__builtin_amdgcn_fdot2)
    return __builtin_amdgcn_fdot2(a, b, c, false);
#else
    return c + (float)a.x * (float)b.x + (float)a.y * (float)b.y;
#endif
}

// fused DPP add: p += rotate_within_16(p); pure VALU, no LDS pipe
template<int CTRL>
__device__ __forceinline__ float dppadd(float p) {
    int s = __builtin_amdgcn_update_dpp(0, __builtin_bit_cast(int, p),
                                        CTRL, 0xf, 0xf, false);
    return p + __builtin_bit_cast(float, s);
}
// sum over each 32-lane half: 4 DPP row_ror adds (16-lane rows) + 1 xor16 swizzle
__device__ __forceinline__ float half_reduce(float p) {
    p = dppadd<0x121>(p);   // row_ror:1
    p = dppadd<0x122>(p);   // row_ror:2
    p = dppadd<0x124>(p);   // row_ror:4
    p = dppadd<0x128>(p);   // row_ror:8
    p += __builtin_bit_cast(float,
         __builtin_amdgcn_ds_swizzle(__builtin_bit_cast(int, p), 0x401F));
    return p;
}

// ---- register-tiled GEMM: 64 rows/block, 16 rows/wave, W amortized 16x -----
__device__ __forceinline__ void gemm_tile64(
    const float* __restrict__ X, const float* __restrict__ W,
    const float* __restrict__ bias, unsigned* __restrict__ Yp,
    int nrows, int tb, float* Xs /* [64*64] */)
{
    int row0 = tb * 64;
    const float4* X4 = (const float4*)(X + (size_t)row0 * 64);
    float4* Xs4 = (float4*)Xs;
#pragma unroll
    for (int gi = 0; gi < 4; ++gi) {
        int g = threadIdx.x + gi * 256;
        float4 v = {0.f, 0.f, 0.f, 0.f};
        if (row0 + (g >> 4) < nrows) v = X4[g];
        Xs4[g] = v;
    }
    __syncthreads();
    int wv = threadIdx.x >> 6, lane = threadIdx.x & 63;
    const float* Xw = Xs + (wv * 16) * 64;
    float2 bb = *(const float2*)(bias + lane * 2);
    float2 acc[16];
#pragma unroll
    for (int r = 0; r < 16; ++r) acc[r] = bb;
#pragma unroll 4
    for (int k4 = 0; k4 < 16; ++k4) {
        float2 w0 = *(const float2*)(W + (k4 * 4 + 0) * 128 + lane * 2);
        float2 w1 = *(const float2*)(W + (k4 * 4 + 1) * 128 + lane * 2);
        float2 w2 = *(const float2*)(W + (k4 * 4 + 2) * 128 + lane * 2);
        float2 w3 = *(const float2*)(W + (k4 * 4 + 3) * 128 + lane * 2);
#pragma unroll
        for (int r = 0; r < 16; ++r) {
            float4 xv = *(const float4*)(Xw + r * 64 + k4 * 4);
            acc[r].x += xv.x * w0.x + xv.y * w1.x + xv.z * w2.x + xv.w * w3.x;
            acc[r].y += xv.x * w0.y + xv.y * w1.y + xv.z * w2.y + xv.w * w3.y;
        }
    }
#pragma unroll
    for (int r = 0; r < 16; ++r) {
        int row = row0 + wv * 16 + r;
        if (row < nrows) Yp[(size_t)row * 64 + lane] = pack_f16(acc[r].x, acc[r].y);
    }
}

// residual GEMM: Y[N,64] = X[N,64] @ W[64,64], f32 out (no bias)
__device__ __forceinline__ void gemm_tile64_res(
    const float* __restrict__ X, const float* __restrict__ W,
    float* __restrict__ Y, int nrows, int tb, float* Xs)
{
    int row0 = tb * 64;
    const float4* X4 = (const float4*)(X + (size_t)row0 * 64);
    float4* Xs4 = (float4*)Xs;
#pragma unroll
    for (int gi = 0; gi < 4; ++gi) {
        int g = threadIdx.x + gi * 256;
        float4 v = {0.f, 0.f, 0.f, 0.f};
        if (row0 + (g >> 4) < nrows) v = X4[g];
        Xs4[g] = v;
    }
    __syncthreads();
    int wv = threadIdx.x >> 6, lane = threadIdx.x & 63;
    const float* Xw = Xs + (wv * 16) * 64;
    float acc[16];
#pragma unroll
    for (int r = 0; r < 16; ++r) acc[r] = 0.f;
#pragma unroll 4
    for (int k4 = 0; k4 < 16; ++k4) {
        float w0 = W[(k4 * 4 + 0) * 64 + lane];
        float w1 = W[(k4 * 4 + 1) * 64 + lane];
        float w2 = W[(k4 * 4 + 2) * 64 + lane];
        float w3 = W[(k4 * 4 + 3) * 64 + lane];
#pragma unroll
        for (int r = 0; r < 16; ++r) {
            float4 xv = *(const float4*)(Xw + r * 64 + k4 * 4);
            acc[r] += xv.x * w0 + xv.y * w1 + xv.z * w2 + xv.w * w3;
        }
    }
#pragma unroll
    for (int r = 0; r < 16; ++r) {
        int row = row0 + wv * 16 + r;
        if (row < nrows) Y[(size_t)row * 64 + lane] = acc[r];
    }
}

// ---- fused prologue: all GAT-independent work, block-range dispatched ------
// [0,11719):       ea -> f16 pairs (2 float4/thread, two coalesced passes)
// [11719,12501):   x_l gemm tiles (782)
// [12501,14064):   x_r gemm tiles (1563)
// [14064,15627):   res gemm tiles (1563)
// [15627,17092):   dst histogram (1465)
// [17092,23342):   concat copy out[:,64:] = task_x (6250)
// [23342]:         pack W_e k-pairs
#define FP_XL0   11719
#define FP_XR0   12501
#define FP_RES0  14064
#define FP_HIST0 15627
#define FP_CAT0  17092
#define FP_WP    23342
__global__ __launch_bounds__(256) void fused_pre(
    const float* __restrict__ data_x, const float* __restrict__ Wl,
    const float* __restrict__ bl,
    const float* __restrict__ task_x, const float* __restrict__ Wr,
    const float* __restrict__ br,
    const float* __restrict__ Wres, const float* __restrict__ We,
    const float* __restrict__ ea, const int* __restrict__ dst,
    unsigned* __restrict__ xlb, unsigned* __restrict__ xrb,
    float* __restrict__ res, uint2* __restrict__ eafu2,
    unsigned* __restrict__ Wp, int* __restrict__ hist,
    float* __restrict__ out)
{
    __shared__ float Xs[64 * 64];
    int b = blockIdx.x;
    if (b < FP_XL0) {
        int g = b * 256 + threadIdx.x;          // [0, 3M)
#pragma unroll
        for (int h = 0; h < 2; ++h) {
            int idx = g + h * 3000000;          // 6M float4 total
            float4 q = ((const float4*)ea)[idx];
            uint2 o;
            o.x = pack_f16(q.x, q.y);
            o.y = pack_f16(q.z, q.w);
            eafu2[idx] = o;
        }
    } else if (b < FP_XR0) {
        gemm_tile64(data_x, Wl, bl, xlb, N_DATA, b - FP_XL0, Xs);
    } else if (b < FP_RES0) {
        gemm_tile64(task_x, Wr, br, xrb, N_TASK, b - FP_XR0, Xs);
    } else if (b < FP_HIST0) {
        gemm_tile64_res(task_x, Wres, res, N_TASK, b - FP_RES0, Xs);
    } else if (b < FP_CAT0) {
        int g = (b - FP_HIST0) * 256 + threadIdx.x;
        if (g < NE / 4) {
            int4 d = ((const int4*)dst)[g];
            atomicAdd(&hist[d.x], 1);
            atomicAdd(&hist[d.y], 1);
            atomicAdd(&hist[d.z], 1);
            atomicAdd(&hist[d.w], 1);
        }
    } else if (b < FP_WP) {
        int g = (b - FP_CAT0) * 256 + threadIdx.x;   // float4 idx over [100k,64]
        if (g < N_TASK * 16) {
            int n = g >> 4, c4 = g & 15;
            float4 v = ((const float4*)task_x)[g];
            ((float4*)out)[(size_t)n * 32 + 16 + c4] = v;
        }
    } else {
#pragma unroll
        for (int r = 0; r < 4; ++r) {
            int idx = threadIdx.x * 4 + r;          // kp*128 + col
            int kp = idx >> 7, col = idx & 127;
            Wp[idx] = pack_f16(We[(2 * kp) * 128 + col],
                               We[(2 * kp + 1) * 128 + col]);
        }
    }
}

// ---- single-kernel decoupled-lookback exclusive scan -----------------------
__global__ __launch_bounds__(SCAN_B) void scan_lookback(
    const int* __restrict__ hist, unsigned long long* __restrict__ flags,
    int* __restrict__ start, int* __restrict__ cursor)
{
    __shared__ int s[SCAN_B];
    __shared__ int ex_sh;
    int tid = threadIdx.x, b = blockIdx.x;
    int i = b * SCAN_B + tid;
    int v = (i < N_TASK) ? hist[i] : 0;
    s[tid] = v;
    __syncthreads();
#pragma unroll
    for (int off = 1; off < SCAN_B; off <<= 1) {
        int t = (tid >= off) ? s[tid - off] : 0;
        __syncthreads();
        s[tid] += t;
        __syncthreads();
    }
    int incl = s[tid];
    if (tid == 0) {
        int total = s[SCAN_B - 1];
        __hip_atomic_store(&flags[b], (1ULL << 32) | (unsigned)total,
                           __ATOMIC_RELEASE, __HIP_MEMORY_SCOPE_AGENT);
        int ex = 0;
        for (int p = b - 1; p >= 0; --p) {
            unsigned long long f;
            do {
                f = __hip_atomic_load(&flags[p], __ATOMIC_ACQUIRE,
                                      __HIP_MEMORY_SCOPE_AGENT);
            } while ((f >> 32) == 0ULL);
            ex += (int)(unsigned)f;
            if ((f >> 32) == 2ULL) break;
        }
        __hip_atomic_store(&flags[b], (2ULL << 32) | (unsigned)(ex + total),
                           __ATOMIC_RELEASE, __HIP_MEMORY_SCOPE_AGENT);
        ex_sh = ex;
    }
    __syncthreads();
    if (i < N_TASK) {
        int st = ex_sh + incl - v;
        start[i] = st;
        cursor[i] = st;
    }
}

// ---- sort scatter: (src, eid) into dst-sorted order (8 B random writes) ----
__global__ __launch_bounds__(256) void scatter_sort(
    const int* __restrict__ src, const int* __restrict__ dst,
    int* __restrict__ cursor, int2* __restrict__ sedge)
{
    int e = blockIdx.x * blockDim.x + threadIdx.x;
    if (e >= NE) return;
    int d = dst[e];
    int pos = atomicAdd(&cursor[d], 1);
    sedge[pos] = make_int2(src[e], e);
}

// ---- fused GAT + softmax + (precomputed residual) + LayerNorm --------------
// one wave per task node; lane l: channels (2l,2l+1) i.e. cols 2l,2l+1 of [H*C]
__global__ __launch_bounds__(256) void node_gat(
    const unsigned* __restrict__ xlb, const unsigned* __restrict__ xrb,
    const uint4* __restrict__ eaf, const unsigned* __restrict__ Wp,
    const float* __restrict__ att,
    const int* __restrict__ seg_start, const int* __restrict__ seg_cnt,
    const int2* __restrict__ sedge,
    const float* __restrict__ res, const float* __restrict__ bias,
    const float* __restrict__ g, const float* __restrict__ beta,
    float* __restrict__ out)
{
    int lane = threadIdx.x & 63;
    int li = lane & 31;
    int n = blockIdx.x * 4 + (threadIdx.x >> 6);
    if (n >= N_TASK) return;

    // W_e k-pair fragments for this lane's two columns
    const uint2* Wp2 = (const uint2*)Wp;
    uint2 wp0 = Wp2[0 * 64 + lane], wp1 = Wp2[1 * 64 + lane];
    uint2 wp2 = Wp2[2 * 64 + lane], wp3 = Wp2[3 * 64 + lane];
    uint2 wp4 = Wp2[4 * 64 + lane], wp5 = Wp2[5 * 64 + lane];
    uint2 wp6 = Wp2[6 * 64 + lane], wp7 = Wp2[7 * 64 + lane];

    half2v xrh = __builtin_bit_cast(half2v, xrb[(unsigned)(n * 64 + lane)]);
    // att scaled by log2(e): exp(p) == exp2(p') with the scale folded in
    float2 atf = *(const float2*)(att + lane * 2);
    half2v ath = {(_Float16)(atf.x * 1.44269504f), (_Float16)(atf.y * 1.44269504f)};
    const half2v hpt2 = {(_Float16)0.2f, (_Float16)0.2f};

    int beg = __builtin_amdgcn_readfirstlane(seg_start[n]);
    int cnt = __builtin_amdgcn_readfirstlane(seg_cnt[n]);

    half2v acch = {(_Float16)0.f, (_Float16)0.f};
    float den = 0.f;

    // p' (log2-domain pre-reduce alpha contribution) for one edge, packed f16
    auto palpha = [&](unsigned xu, uint4 u0, uint4 u1) -> float {
        float ev0 = 0.f, ev1 = 0.f;
        ev0 = fdot2f(u0.x, wp0.x, ev0); ev1 = fdot2f(u0.x, wp0.y, ev1);
        ev0 = fdot2f(u0.y, wp1.x, ev0); ev1 = fdot2f(u0.y, wp1.y, ev1);
        ev0 = fdot2f(u0.z, wp2.x, ev0); ev1 = fdot2f(u0.z, wp2.y, ev1);
        ev0 = fdot2f(u0.w, wp3.x, ev0); ev1 = fdot2f(u0.w, wp3.y, ev1);
        ev0 = fdot2f(u1.x, wp4.x, ev0); ev1 = fdot2f(u1.x, wp4.y, ev1);
        ev0 = fdot2f(u1.y, wp5.x, ev0); ev1 = fdot2f(u1.y, wp5.y, ev1);
        ev0 = fdot2f(u1.z, wp6.x, ev0); ev1 = fdot2f(u1.z, wp6.y, ev1);
        ev0 = fdot2f(u1.w, wp7.x, ev0); ev1 = fdot2f(u1.w, wp7.y, ev1);
        half2v z = __builtin_bit_cast(half2v, xu) + xrh
                 + __builtin_amdgcn_cvt_pkrtz(ev0, ev1);
        half2v z2 = z * hpt2;
#if __has_builtin(__builtin_elementwise_max)
        half2v lr = __builtin_elementwise_max(z, z2);
#else
        half2v lr; lr.x = z.x > z2.x ? z.x : z2.x; lr.y = z.y > z2.y ? z.y : z2.y;
#endif
        return fdot2h(lr, ath, 0.f);
    };
    auto accum = [&](float w, unsigned xu) {
        _Float16 wh = (_Float16)w;
        half2v w2 = {wh, wh};
        acch = acch + w2 * __builtin_bit_cast(half2v, xu);   // v_pk_fma_f16
        den += w;
    };

#define PAYLOAD(se, xu, e0, e1) do {                                         \
    int s_ = __builtin_amdgcn_readfirstlane((se).x);                         \
    int e_ = __builtin_amdgcn_readfirstlane((se).y);                         \
    xu = xlb[(unsigned)(s_ * 64 + lane)];                                    \
    const uint4* p_ = eaf + (unsigned)(e_ * 2);                              \
    e0 = p_[0]; e1 = p_[1];                                                  \
} while (0)

    // depth-2 payload slots + depth-4 index prefetch
    int2 se0 = {0, 0}, se1 = {0, 0};
    unsigned xuA = 0, xuB = 0;
    uint4 A0 = {0,0,0,0}, A1 = {0,0,0,0}, B0 = {0,0,0,0}, B1 = {0,0,0,0};
    if (cnt > 0) se0 = sedge[beg];
    if (cnt > 1) se1 = sedge[beg + 1];
    if (cnt > 0) PAYLOAD(se0, xuA, A0, A1);
    if (cnt > 1) PAYLOAD(se1, xuB, B0, B1);
    if (cnt > 2) se0 = sedge[beg + 2];
    if (cnt > 3) se1 = sedge[beg + 3];

    int i = 0;
    for (; i + 2 <= cnt; i += 2) {
        float pA = palpha(xuA, A0, A1);
        float pB = palpha(xuB, B0, B1);
        unsigned cA = xuA, cB = xuB;
        if (i + 2 < cnt) PAYLOAD(se0, xuA, A0, A1);
        if (i + 3 < cnt) PAYLOAD(se1, xuB, B0, B1);
        if (i + 4 < cnt) se0 = sedge[beg + i + 4];
        if (i + 5 < cnt) se1 = sedge[beg + i + 5];
        pA = half_reduce(pA);
        pB = half_reduce(pB);
        accum(__builtin_amdgcn_exp2f(pA), cA);
        accum(__builtin_amdgcn_exp2f(pB), cB);
    }
    if (i < cnt) {   // odd leftover sits in slot A
        float p = half_reduce(palpha(xuA, A0, A1));
        accum(__builtin_amdgcn_exp2f(p), xuA);
    }
#undef PAYLOAD

    float inv = 1.f / (den + 1e-16f);        // cnt==0 -> acc=0 -> matches ref
    float o0 = (float)acch.x * inv, o1 = (float)acch.y * inv;

    // head mean across the two 32-lane halves
    float m0 = 0.5f * (o0 + __shfl_xor(o0, 32));
    float m1 = 0.5f * (o1 + __shfl_xor(o1, 32));

    // precomputed residual (lanes l and l+32 load the same addr -> broadcast)
    float2 r2 = *(const float2*)(res + (unsigned)(n * 64 + li * 2));
    float o0f = m0 + r2.x + bias[li * 2];
    float o1f = m1 + r2.y + bias[li * 2 + 1];

    // LayerNorm over 64 channels (2/lane across each 32-lane half)
    float sum = o0f + o1f, ssq = o0f * o0f + o1f * o1f;
    sum = half_reduce(sum);
    ssq = half_reduce(ssq);
    float mu = sum * (1.f / 64.f);
    float var = ssq * (1.f / 64.f) - mu * mu;
    float is = rsqrtf(var + 1e-5f);
    float x0o = (o0f - mu) * is * g[li * 2]     + beta[li * 2];
    float x1o = (o1f - mu) * is * g[li * 2 + 1] + beta[li * 2 + 1];
    x0o = x0o > 0.f ? x0o : 0.01f * x0o;
    x1o = x1o > 0.f ? x1o : 0.01f * x1o;

    if (lane < 32) {
        float2 o = {x0o, x1o};
        *(float2*)(out + (size_t)n * 128 + li * 2) = o;
    }
    // out[:,64:] (concat of task_x) is written by fused_pre
}

extern "C" void kernel_launch(void* const* d_in, const int* in_sizes, int n_in,
                              void* d_out, int out_size, void* d_ws, size_t ws_size,
                              hipStream_t stream)
{
    const float* task_x    = (const float*)d_in[0];
    const float* data_x    = (const float*)d_in[1];
    const float* edge_attr = (const float*)d_in[2];
    const int*   src_idx   = (const int*)d_in[3];
    const int*   dst_idx   = (const int*)d_in[4];
    const float* W_l       = (const float*)d_in[5];
    const float* b_l       = (const float*)d_in[6];
    const float* W_r       = (const float*)d_in[7];
    const float* b_r       = (const float*)d_in[8];
    const float* W_e       = (const float*)d_in[9];
    const float* att       = (const float*)d_in[10];
    const float* W_res     = (const float*)d_in[11];
    const float* conv_bias = (const float*)d_in[12];
    const float* ln_g      = (const float*)d_in[13];
    const float* ln_b      = (const float*)d_in[14];
    float* out = (float*)d_out;

    // workspace layout (~126 MB)
    unsigned* xlb  = (unsigned*)d_ws;                  // 3,200,000 u32 (x_l f16)
    unsigned* xrb  = xlb + 3200000;                    // 6,400,000 u32 (x_r f16)
    uint4*    eaf  = (uint4*)(xrb + 6400000);          // 3,000,000 uint4 (ea f16)
    float*    res  = (float*)(eaf + 3000000);          // 6,400,000 f (residual)
    unsigned* Wp   = (unsigned*)(res + 6400000);       // 1,024 (W_e k-pairs)
    int*      hist = (int*)(Wp + 1024);                // 100,000
    unsigned long long* flags = (unsigned long long*)(hist + 100000); // 128
    int*     start = (int*)(flags + 128);              // 100,000
    int*    cursor = start + 100000;                   // 100,000
    int2*    sedge = (int2*)(cursor + 100000);         // 1,500,000 int2

    // zero hist + flags (stream-ordered, graph-capturable)
    hipMemsetAsync(hist, 0, 100000 * sizeof(int) + 128 * sizeof(unsigned long long),
                   stream);
    fused_pre    <<<23343, 256, 0, stream>>>(data_x, W_l, b_l, task_x, W_r, b_r,
                                             W_res, W_e, edge_attr, dst_idx,
                                             xlb, xrb, res, (uint2*)eaf, Wp, hist,
                                             out);
    scan_lookback<<<NB_SCAN, SCAN_B, 0, stream>>>(hist, flags, start, cursor);
    scatter_sort <<<5860, 256, 0, stream>>>(src_idx, dst_idx, cursor, sedge);
    node_gat     <<<25000, 256, 0, stream>>>(xlb, xrb, eaf, Wp, att,
                                             start, hist, sedge,
                                             res, conv_bias, ln_g, ln_b, out);
}